// Round 1
// baseline (1123.297 us; speedup 1.0000x reference)
//
#include <hip/hip_runtime.h>
#include <math.h>

#define NN 100000
#define NE 1600000
#define HID 64

// ---------------- norm pipeline ----------------

__global__ void k_zero(float* __restrict__ p, int n) {
    int i = blockIdx.x * blockDim.x + threadIdx.x;
    if (i < n) p[i] = 0.0f;
}

__global__ void k_deg(const int* __restrict__ dst, float* __restrict__ deg, int E) {
    int e = blockIdx.x * blockDim.x + threadIdx.x;
    if (e < E) atomicAdd(&deg[dst[e]], 1.0f);
}

__global__ void k_dinv(float* __restrict__ deg, int n) {
    int i = blockIdx.x * blockDim.x + threadIdx.x;
    if (i < n) {
        float d = deg[i];
        deg[i] = (d > 0.0f) ? (1.0f / sqrtf(d)) : 0.0f;
    }
}

__global__ void k_norm(const int* __restrict__ src, const int* __restrict__ dst,
                       const float* __restrict__ dinv, float* __restrict__ norm, int E) {
    int e = blockIdx.x * blockDim.x + threadIdx.x;
    if (e < E) norm[e] = dinv[src[e]] * dinv[dst[e]];
}

// ---------------- dense kernels ----------------

// layer1: x[N,10] -> h = xW [N,64], y = xV + b [N,64]. One 64-lane block per node.
__global__ void k_dense1(const float* __restrict__ x, const float* __restrict__ W,
                         const float* __restrict__ V, const float* __restrict__ b,
                         float* __restrict__ h, float* __restrict__ y) {
    __shared__ float sx[16];
    int n = blockIdx.x;
    int f = threadIdx.x;  // 0..63
    if (f < 10) sx[f] = x[n * 10 + f];
    __syncthreads();
    float ah = 0.0f, ay = 0.0f;
#pragma unroll
    for (int k = 0; k < 10; ++k) {
        float xv = sx[k];
        ah += xv * W[k * HID + f];
        ay += xv * V[k * HID + f];
    }
    h[n * HID + f] = ah;
    y[n * HID + f] = ay + b[f];
}

// mid: xin[N,64] -> h = xin*W [N,64], y = xin*V + b [N,64]. y may alias xin (safe:
// each block reads only its own row into LDS before writing it).
__global__ void k_dense64(const float* __restrict__ xin, const float* __restrict__ W,
                          const float* __restrict__ V, const float* __restrict__ b,
                          float* __restrict__ h, float* __restrict__ y) {
    __shared__ float sx[HID];
    int n = blockIdx.x;
    int f = threadIdx.x;
    sx[f] = xin[n * HID + f];
    __syncthreads();
    float ah = 0.0f, ay = 0.0f;
#pragma unroll
    for (int k = 0; k < HID; ++k) {
        float xv = sx[k];
        ah += xv * W[k * HID + f];
        ay += xv * V[k * HID + f];
    }
    h[n * HID + f] = ah;
    y[n * HID + f] = ay + b[f];
}

// layer3: xin[N,64] -> h3 = xin*W3 [N,2], y3 = xin*V3 + b3 [N,2].
// 64 threads handle a 64-node tile staged in LDS (padded stride 65).
__global__ void k_dense3(const float* __restrict__ xin, const float* __restrict__ W,
                         const float* __restrict__ V, const float* __restrict__ b,
                         float* __restrict__ h, float* __restrict__ y, int N) {
    __shared__ float s[64][65];
    int base = blockIdx.x * 64;
    int lane = threadIdx.x;
#pragma unroll 8
    for (int r = 0; r < 64; ++r) {
        int n = base + r;
        s[r][lane] = (n < N) ? xin[n * HID + lane] : 0.0f;
    }
    __syncthreads();
    int n = base + lane;
    if (n < N) {
        float h0 = 0, h1 = 0, y0 = 0, y1 = 0;
#pragma unroll
        for (int k = 0; k < HID; ++k) {
            float xv = s[lane][k];
            h0 += xv * W[k * 2 + 0];
            h1 += xv * W[k * 2 + 1];
            y0 += xv * V[k * 2 + 0];
            y1 += xv * V[k * 2 + 1];
        }
        h[n * 2 + 0] = h0;
        h[n * 2 + 1] = h1;
        y[n * 2 + 0] = y0 + b[0];
        y[n * 2 + 1] = y1 + b[1];
    }
}

// ---------------- scatter (message passing) ----------------

// wave-per-edge, lane = feature. out[dst][f] += norm[e] * h[src][f]
__global__ void k_scatter64(const int* __restrict__ src, const int* __restrict__ dst,
                            const float* __restrict__ norm, const float* __restrict__ h,
                            float* __restrict__ out, int E) {
    int g = blockIdx.x * blockDim.x + threadIdx.x;
    int e = g >> 6;
    int f = g & 63;
    if (e < E) {
        float v = norm[e] * h[src[e] * HID + f];
        atomicAdd(&out[dst[e] * HID + f], v);
    }
}

__global__ void k_scatter2(const int* __restrict__ src, const int* __restrict__ dst,
                           const float* __restrict__ norm, const float* __restrict__ h,
                           float* __restrict__ out, int E) {
    int g = blockIdx.x * blockDim.x + threadIdx.x;
    int e = g >> 1;
    int f = g & 1;
    if (e < E) {
        float v = norm[e] * h[src[e] * 2 + f];
        atomicAdd(&out[dst[e] * 2 + f], v);
    }
}

// ---------------- pointwise ----------------

__global__ void k_relu(float* __restrict__ p, int n) {
    int i = blockIdx.x * blockDim.x + threadIdx.x;
    if (i < n) p[i] = fmaxf(p[i], 0.0f);
}

__global__ void k_lsm(const float* __restrict__ y, float* __restrict__ out, int N) {
    int n = blockIdx.x * blockDim.x + threadIdx.x;
    if (n < N) {
        float z0 = y[n * 2 + 0], z1 = y[n * 2 + 1];
        float m = fmaxf(z0, z1);
        float l = m + logf(expf(z0 - m) + expf(z1 - m));
        out[n * 2 + 0] = z0 - l;
        out[n * 2 + 1] = z1 - l;
    }
}

// ---------------- launch ----------------

extern "C" void kernel_launch(void* const* d_in, const int* in_sizes, int n_in,
                              void* d_out, int out_size, void* d_ws, size_t ws_size,
                              hipStream_t stream) {
    const float* x  = (const float*)d_in[0];
    const int*   ei = (const int*)d_in[1];
    const int*   src = ei;
    const int*   dst = ei + NE;
    const float* W1 = (const float*)d_in[2];
    const float* V1 = (const float*)d_in[3];
    const float* b1 = (const float*)d_in[4];
    const float* W2 = (const float*)d_in[5];
    const float* V2 = (const float*)d_in[6];
    const float* b2 = (const float*)d_in[7];
    const float* W3 = (const float*)d_in[8];
    const float* V3 = (const float*)d_in[9];
    const float* b3 = (const float*)d_in[10];
    float* out = (float*)d_out;

    float* ws   = (float*)d_ws;
    float* deg  = ws;                    // NN floats (becomes dinv in place)
    float* norm = ws + 100352;           // NE floats
    float* h    = norm + NE;             // NN*64 floats
    float* t    = h + NN * HID;          // NN*64 floats
    float* h3   = h;                     // NN*2 (reuse h region in layer 3)
    float* o3   = h + 200704;            // NN*2

    const int B = 256;

    // gcn_norm
    k_zero<<<(NN + B - 1) / B, B, 0, stream>>>(deg, NN);
    k_deg<<<(NE + B - 1) / B, B, 0, stream>>>(dst, deg, NE);
    k_dinv<<<(NN + B - 1) / B, B, 0, stream>>>(deg, NN);
    k_norm<<<(NE + B - 1) / B, B, 0, stream>>>(src, dst, deg, norm, NE);

    // layer 1: h = x@W1, t = x@V1 + b1; t += scatter(norm*h[src]); relu(t)
    k_dense1<<<NN, 64, 0, stream>>>(x, W1, V1, b1, h, t);
    {
        long long tot = (long long)NE * HID;
        k_scatter64<<<(int)((tot + B - 1) / B), B, 0, stream>>>(src, dst, norm, h, t, NE);
    }
    k_relu<<<(NN * HID + B - 1) / B, B, 0, stream>>>(t, NN * HID);

    // layer 2 (in-place on t)
    k_dense64<<<NN, 64, 0, stream>>>(t, W2, V2, b2, h, t);
    {
        long long tot = (long long)NE * HID;
        k_scatter64<<<(int)((tot + B - 1) / B), B, 0, stream>>>(src, dst, norm, h, t, NE);
    }
    k_relu<<<(NN * HID + B - 1) / B, B, 0, stream>>>(t, NN * HID);

    // layer 3
    k_dense3<<<(NN + 63) / 64, 64, 0, stream>>>(t, W3, V3, b3, h3, o3, NN);
    {
        long long tot = (long long)NE * 2;
        k_scatter2<<<(int)((tot + B - 1) / B), B, 0, stream>>>(src, dst, norm, h3, o3, NE);
    }
    k_lsm<<<(NN + B - 1) / B, B, 0, stream>>>(o3, out, NN);
}

// Round 2
// 644.911 us; speedup vs baseline: 1.7418x; 1.7418x over previous
//
#include <hip/hip_runtime.h>
#include <math.h>

#define NN 100000
#define NE 1600000
#define HID 64
#define SCAN_T 1024
#define SCAN_NB 98   // ceil(100000/1024)

// ---------------- utility ----------------

__global__ void k_zero_i(int* __restrict__ p, int n) {
    int i = blockIdx.x * blockDim.x + threadIdx.x;
    if (i < n) p[i] = 0;
}

// ---------------- CSR build ----------------

__global__ void k_count(const int* __restrict__ dst, int* __restrict__ cnt, int E) {
    int e = blockIdx.x * blockDim.x + threadIdx.x;
    if (e < E) atomicAdd(&cnt[dst[e]], 1);
}

__global__ void k_dinv(const int* __restrict__ cnt, float* __restrict__ dinv, int n) {
    int i = blockIdx.x * blockDim.x + threadIdx.x;
    if (i < n) {
        int c = cnt[i];
        dinv[i] = (c > 0) ? (1.0f / sqrtf((float)c)) : 0.0f;
    }
}

__global__ void k_scan1(const int* __restrict__ cnt, int* __restrict__ rp,
                        int* __restrict__ bsum, int n) {
    __shared__ int s[SCAN_T];
    int t = threadIdx.x;
    int i = blockIdx.x * SCAN_T + t;
    int v = (i < n) ? cnt[i] : 0;
    s[t] = v;
    __syncthreads();
    for (int off = 1; off < SCAN_T; off <<= 1) {
        int u = (t >= off) ? s[t - off] : 0;
        __syncthreads();
        s[t] += u;
        __syncthreads();
    }
    if (i < n) rp[i] = s[t] - v;  // exclusive
    if (t == SCAN_T - 1) bsum[blockIdx.x] = s[t];
}

__global__ void k_scan2(int* __restrict__ bsum, int nb) {
    __shared__ int s[128];
    int t = threadIdx.x;
    int v = (t < nb) ? bsum[t] : 0;
    s[t] = v;
    __syncthreads();
    for (int off = 1; off < 128; off <<= 1) {
        int u = (t >= off) ? s[t - off] : 0;
        __syncthreads();
        s[t] += u;
        __syncthreads();
    }
    if (t < nb) bsum[t] = s[t] - v;  // exclusive
}

__global__ void k_scan3(int* __restrict__ rp, const int* __restrict__ bsum, int n, int total) {
    int i = blockIdx.x * SCAN_T + threadIdx.x;
    if (i < n) rp[i] += bsum[blockIdx.x];
    if (i == 0) rp[n] = total;
}

// fill CSR: perm[slot] = src of edge (grouped by dst). cur is a zeroed cursor.
__global__ void k_fill(const int* __restrict__ src, const int* __restrict__ dst,
                       const int* __restrict__ rp, int* __restrict__ cur,
                       int* __restrict__ perm, int E) {
    int e = blockIdx.x * blockDim.x + threadIdx.x;
    if (e < E) {
        int d = dst[e];
        int pos = rp[d] + atomicAdd(&cur[d], 1);
        perm[pos] = src[e];
    }
}

// ---------------- aggregation (gather, no atomics) ----------------

// aggx[n,10] = dinv[n] * sum_{s in N(n)} dinv[s] * x[s,0:10]   (thread per node)
__global__ void k_aggx(const int* __restrict__ rp, const int* __restrict__ perm,
                       const float* __restrict__ dinv, const float* __restrict__ x,
                       float* __restrict__ aggx, int N) {
    int n = blockIdx.x * blockDim.x + threadIdx.x;
    if (n >= N) return;
    int beg = rp[n], end = rp[n + 1];
    float acc[10];
#pragma unroll
    for (int k = 0; k < 10; ++k) acc[k] = 0.0f;
    for (int j = beg; j < end; ++j) {
        int s = perm[j];
        float w = dinv[s];
        const float* xr = x + (size_t)s * 10;
#pragma unroll
        for (int k = 0; k < 10; ++k) acc[k] += w * xr[k];
    }
    float dn = dinv[n];
#pragma unroll
    for (int k = 0; k < 10; ++k) aggx[(size_t)n * 10 + k] = dn * acc[k];
}

// aggt[n,64] = dinv[n] * sum dinv[s] * t[s,0:64]   (wave per node, lane = feature)
__global__ void k_agg64(const int* __restrict__ rp, const int* __restrict__ perm,
                        const float* __restrict__ dinv, const float* __restrict__ hs,
                        float* __restrict__ outp, int N) {
    int wid = (blockIdx.x * blockDim.x + threadIdx.x) >> 6;
    if (wid >= N) return;
    int n = __builtin_amdgcn_readfirstlane(wid);
    int f = threadIdx.x & 63;
    int beg = rp[n], end = rp[n + 1];
    float acc = 0.0f;
    int j = beg;
    for (; j + 1 < end; j += 2) {
        int s0 = perm[j], s1 = perm[j + 1];
        float w0 = dinv[s0], w1 = dinv[s1];
        float v0 = hs[(size_t)s0 * HID + f];
        float v1 = hs[(size_t)s1 * HID + f];
        acc += w0 * v0;
        acc += w1 * v1;
    }
    if (j < end) {
        int s = perm[j];
        acc += dinv[s] * hs[(size_t)s * HID + f];
    }
    outp[(size_t)n * HID + f] = dinv[n] * acc;
}

// layer-3 aggregation (2-wide) + log_softmax, thread per node
__global__ void k_agg3lsm(const int* __restrict__ rp, const int* __restrict__ perm,
                          const float* __restrict__ dinv, const float2* __restrict__ h3,
                          const float2* __restrict__ y3, float* __restrict__ out, int N) {
    int n = blockIdx.x * blockDim.x + threadIdx.x;
    if (n >= N) return;
    int beg = rp[n], end = rp[n + 1];
    float a0 = 0.0f, a1 = 0.0f;
    for (int j = beg; j < end; ++j) {
        int s = perm[j];
        float w = dinv[s];
        float2 hh = h3[s];
        a0 += w * hh.x;
        a1 += w * hh.y;
    }
    float dn = dinv[n];
    float2 yy = y3[n];
    float z0 = dn * a0 + yy.x;
    float z1 = dn * a1 + yy.y;
    float m = fmaxf(z0, z1);
    float l = m + logf(expf(z0 - m) + expf(z1 - m));
    out[n * 2 + 0] = z0 - l;
    out[n * 2 + 1] = z1 - l;
}

// ---------------- fused dense ----------------

// t = relu(aggx @ W1 + x @ V1 + b1);  W1,V1: [10,64]. 4 nodes/block (4 waves).
__global__ void k_dense1f(const float* __restrict__ aggx, const float* __restrict__ x,
                          const float* __restrict__ W, const float* __restrict__ V,
                          const float* __restrict__ b, float* __restrict__ tout, int N) {
    __shared__ float sW[640], sV[640];
    for (int i = threadIdx.x; i < 640; i += 256) { sW[i] = W[i]; sV[i] = V[i]; }
    __syncthreads();
    int idx = blockIdx.x * 4 + (threadIdx.x >> 6);
    if (idx >= N) return;
    int f = threadIdx.x & 63;
    float av = (f < 10) ? aggx[(size_t)idx * 10 + f] : 0.0f;
    float xv = (f < 10) ? x[(size_t)idx * 10 + f] : 0.0f;
    float acc = b[f];
#pragma unroll
    for (int k = 0; k < 10; ++k) {
        acc += __shfl(av, k) * sW[k * HID + f];
        acc += __shfl(xv, k) * sV[k * HID + f];
    }
    tout[(size_t)idx * HID + f] = fmaxf(acc, 0.0f);
}

// t = relu(aggt @ W2 + t @ V2 + b2);  W2,V2: [64,64] in LDS. In-place safe.
__global__ void k_dense2f(const float* __restrict__ aggt, const float* __restrict__ tin,
                          const float* __restrict__ W, const float* __restrict__ V,
                          const float* __restrict__ b, float* __restrict__ tout, int N) {
    __shared__ float sW[4096], sV[4096];
    for (int i = threadIdx.x; i < 4096; i += 256) { sW[i] = W[i]; sV[i] = V[i]; }
    __syncthreads();
    int idx = blockIdx.x * 4 + (threadIdx.x >> 6);
    if (idx >= N) return;
    int f = threadIdx.x & 63;
    float av = aggt[(size_t)idx * HID + f];
    float tv = tin[(size_t)idx * HID + f];
    float acc = b[f];
#pragma unroll
    for (int k = 0; k < HID; ++k) {
        acc += __shfl(av, k) * sW[k * HID + f];
        acc += __shfl(tv, k) * sV[k * HID + f];
    }
    tout[(size_t)idx * HID + f] = fmaxf(acc, 0.0f);
}

// h3 = t @ W3 [N,2], y3 = t @ V3 + b3 [N,2]. 64-node tile through padded LDS.
__global__ void k_dense3(const float* __restrict__ xin, const float* __restrict__ W,
                         const float* __restrict__ V, const float* __restrict__ b,
                         float* __restrict__ h, float* __restrict__ y, int N) {
    __shared__ float s[64][65];
    int base = blockIdx.x * 64;
    int lane = threadIdx.x;
#pragma unroll 8
    for (int r = 0; r < 64; ++r) {
        int n = base + r;
        s[r][lane] = (n < N) ? xin[(size_t)n * HID + lane] : 0.0f;
    }
    __syncthreads();
    int n = base + lane;
    if (n < N) {
        float h0 = 0, h1 = 0, y0 = 0, y1 = 0;
#pragma unroll
        for (int k = 0; k < HID; ++k) {
            float xv = s[lane][k];
            h0 += xv * W[k * 2 + 0];
            h1 += xv * W[k * 2 + 1];
            y0 += xv * V[k * 2 + 0];
            y1 += xv * V[k * 2 + 1];
        }
        h[n * 2 + 0] = h0;
        h[n * 2 + 1] = h1;
        y[n * 2 + 0] = y0 + b[0];
        y[n * 2 + 1] = y1 + b[1];
    }
}

// ---------------- launch ----------------

extern "C" void kernel_launch(void* const* d_in, const int* in_sizes, int n_in,
                              void* d_out, int out_size, void* d_ws, size_t ws_size,
                              hipStream_t stream) {
    const float* x  = (const float*)d_in[0];
    const int*   ei = (const int*)d_in[1];
    const int*   src = ei;
    const int*   dst = ei + NE;
    const float* W1 = (const float*)d_in[2];
    const float* V1 = (const float*)d_in[3];
    const float* b1 = (const float*)d_in[4];
    const float* W2 = (const float*)d_in[5];
    const float* V2 = (const float*)d_in[6];
    const float* b2 = (const float*)d_in[7];
    const float* W3 = (const float*)d_in[8];
    const float* V3 = (const float*)d_in[9];
    const float* b3 = (const float*)d_in[10];
    float* out = (float*)d_out;

    // workspace layout (floats; all offsets multiples of 64 floats = 256 B)
    float* ws = (float*)d_ws;
    int*   cnt  = (int*)ws;                       // [0, 100352)  count, then cursor
    int*   rp   = (int*)(ws + 100352);            // [ , +100608) row_ptr (NN+1)
    float* dinv = ws + 200960;                    // [ , +100352)
    int*   perm = (int*)(ws + 301312);            // [ , +1600000) src grouped by dst
    float* t    = ws + 1901312;                   // [ , +6400000)
    float* R    = ws + 8301312;                   // [ , +6400000) aggx / aggt / h3,y3
    float* aggx = R;                              // NN*10
    float* aggt = R;                              // NN*64
    float* h3   = R;                              // NN*2
    float* y3   = R + 2 * NN;                     // NN*2
    int*   bsum = (int*)(ws + 14701312);          // [ , +128)

    const int B = 256;

    // ---- CSR build + dinv ----
    k_zero_i<<<(NN + B - 1) / B, B, 0, stream>>>(cnt, NN);
    k_count<<<(NE + B - 1) / B, B, 0, stream>>>(dst, cnt, NE);
    k_dinv<<<(NN + B - 1) / B, B, 0, stream>>>(cnt, dinv, NN);
    k_scan1<<<SCAN_NB, SCAN_T, 0, stream>>>(cnt, rp, bsum, NN);
    k_scan2<<<1, 128, 0, stream>>>(bsum, SCAN_NB);
    k_scan3<<<SCAN_NB, SCAN_T, 0, stream>>>(rp, bsum, NN, NE);
    k_zero_i<<<(NN + B - 1) / B, B, 0, stream>>>(cnt, NN);   // reuse as cursor
    k_fill<<<(NE + B - 1) / B, B, 0, stream>>>(src, dst, rp, cnt, perm, NE);

    // ---- layer 1: aggregate x (10-wide) then fused dense ----
    k_aggx<<<(NN + B - 1) / B, B, 0, stream>>>(rp, perm, dinv, x, aggx, NN);
    k_dense1f<<<(NN + 3) / 4, B, 0, stream>>>(aggx, x, W1, V1, b1, t, NN);

    // ---- layer 2: aggregate t (64-wide) then fused dense (in-place on t) ----
    k_agg64<<<(NN * 64 + B - 1) / B, B, 0, stream>>>(rp, perm, dinv, t, aggt, NN);
    k_dense2f<<<(NN + 3) / 4, B, 0, stream>>>(aggt, t, W2, V2, b2, t, NN);

    // ---- layer 3: dense to 2-wide, then aggregate (2-wide) + log_softmax ----
    k_dense3<<<(NN + 63) / 64, 64, 0, stream>>>(t, W3, V3, b3, h3, y3, NN);
    k_agg3lsm<<<(NN + B - 1) / B, B, 0, stream>>>(rp, perm, dinv, (const float2*)h3,
                                                  (const float2*)y3, out, NN);
}

// Round 3
// 502.549 us; speedup vs baseline: 2.2352x; 1.2833x over previous
//
#include <hip/hip_runtime.h>
#include <math.h>

#define NN 100000
#define NE 1600000
#define HID 64
#define SCAN_T 1024
#define SCAN_NB 98   // ceil(100000/1024)

// ---------------- utility ----------------

__global__ void k_zero_i(int* __restrict__ p, int n) {
    int i = blockIdx.x * blockDim.x + threadIdx.x;
    if (i < n) p[i] = 0;
}

// ---------------- CSR build ----------------

__global__ void k_count(const int* __restrict__ dst, int* __restrict__ cnt, int E) {
    int e = blockIdx.x * blockDim.x + threadIdx.x;
    if (e < E) atomicAdd(&cnt[dst[e]], 1);
}

__global__ void k_dinv(const int* __restrict__ cnt, float* __restrict__ dinv, int n) {
    int i = blockIdx.x * blockDim.x + threadIdx.x;
    if (i < n) {
        int c = cnt[i];
        dinv[i] = (c > 0) ? (1.0f / sqrtf((float)c)) : 0.0f;
    }
}

__global__ void k_scan1(const int* __restrict__ cnt, int* __restrict__ rp,
                        int* __restrict__ bsum, int n) {
    __shared__ int s[SCAN_T];
    int t = threadIdx.x;
    int i = blockIdx.x * SCAN_T + t;
    int v = (i < n) ? cnt[i] : 0;
    s[t] = v;
    __syncthreads();
    for (int off = 1; off < SCAN_T; off <<= 1) {
        int u = (t >= off) ? s[t - off] : 0;
        __syncthreads();
        s[t] += u;
        __syncthreads();
    }
    if (i < n) rp[i] = s[t] - v;  // exclusive
    if (t == SCAN_T - 1) bsum[blockIdx.x] = s[t];
}

__global__ void k_scan2(int* __restrict__ bsum, int nb) {
    __shared__ int s[128];
    int t = threadIdx.x;
    int v = (t < nb) ? bsum[t] : 0;
    s[t] = v;
    __syncthreads();
    for (int off = 1; off < 128; off <<= 1) {
        int u = (t >= off) ? s[t - off] : 0;
        __syncthreads();
        s[t] += u;
        __syncthreads();
    }
    if (t < nb) bsum[t] = s[t] - v;  // exclusive
}

__global__ void k_scan3(int* __restrict__ rp, const int* __restrict__ bsum, int n, int total) {
    int i = blockIdx.x * SCAN_T + threadIdx.x;
    if (i < n) rp[i] += bsum[blockIdx.x];
    if (i == 0) rp[n] = total;
}

// fill CSR: perm[slot] = src of edge (grouped by dst). cur is a zeroed cursor.
__global__ void k_fill(const int* __restrict__ src, const int* __restrict__ dst,
                       const int* __restrict__ rp, int* __restrict__ cur,
                       int* __restrict__ perm, int E) {
    int e = blockIdx.x * blockDim.x + threadIdx.x;
    if (e < E) {
        int d = dst[e];
        int pos = rp[d] + atomicAdd(&cur[d], 1);
        perm[pos] = src[e];
    }
}

// ---------------- aggregation (gather, no atomics) ----------------

// aggx[n,10] = dinv[n] * sum_{s in N(n)} dinv[s] * x[s,0:10]   (thread per node)
__global__ void k_aggx(const int* __restrict__ rp, const int* __restrict__ perm,
                       const float* __restrict__ dinv, const float* __restrict__ x,
                       float* __restrict__ aggx, int N) {
    int n = blockIdx.x * blockDim.x + threadIdx.x;
    if (n >= N) return;
    int beg = rp[n], end = rp[n + 1];
    float acc[10];
#pragma unroll
    for (int k = 0; k < 10; ++k) acc[k] = 0.0f;
    for (int j = beg; j < end; ++j) {
        int s = perm[j];
        float w = dinv[s];
        const float* xr = x + (size_t)s * 10;
#pragma unroll
        for (int k = 0; k < 10; ++k) acc[k] += w * xr[k];
    }
    float dn = dinv[n];
#pragma unroll
    for (int k = 0; k < 10; ++k) aggx[(size_t)n * 10 + k] = dn * acc[k];
}

// aggt[n,64] = dinv[n] * sum dinv[s] * t[s,0:64], t in bf16 (ushort).
// Wave per node; lane handles 2 features; 2 edges in flight (half = lane>>5).
__global__ void k_agg64b(const int* __restrict__ rp, const int* __restrict__ perm,
                         const float* __restrict__ dinv, const unsigned short* __restrict__ tb,
                         float* __restrict__ outp, int N) {
    int wid = (blockIdx.x * blockDim.x + threadIdx.x) >> 6;
    if (wid >= N) return;
    int n = __builtin_amdgcn_readfirstlane(wid);
    int lane = threadIdx.x & 63;
    int half = lane >> 5;   // which edge of the pair
    int fh = lane & 31;     // feature-pair index (features 2fh, 2fh+1)
    int beg = rp[n], end = rp[n + 1];
    float acc0 = 0.0f, acc1 = 0.0f;
    for (int j = beg + half; j < end; j += 2) {
        int s = perm[j];
        float w = dinv[s];
        unsigned int u = *(const unsigned int*)(tb + (size_t)s * HID + fh * 2);
        float v0 = __uint_as_float((u & 0xffffu) << 16);
        float v1 = __uint_as_float(u & 0xffff0000u);
        acc0 += w * v0;
        acc1 += w * v1;
    }
    acc0 += __shfl_xor(acc0, 32);
    acc1 += __shfl_xor(acc1, 32);
    if (half == 0) {
        float dn = dinv[n];
        float2 o = make_float2(dn * acc0, dn * acc1);
        *(float2*)(outp + (size_t)n * HID + fh * 2) = o;
    }
}

// layer-3 aggregation (2-wide) + log_softmax, thread per node
__global__ void k_agg3lsm(const int* __restrict__ rp, const int* __restrict__ perm,
                          const float* __restrict__ dinv, const float2* __restrict__ h3,
                          const float2* __restrict__ y3, float* __restrict__ out, int N) {
    int n = blockIdx.x * blockDim.x + threadIdx.x;
    if (n >= N) return;
    int beg = rp[n], end = rp[n + 1];
    float a0 = 0.0f, a1 = 0.0f;
    for (int j = beg; j < end; ++j) {
        int s = perm[j];
        float w = dinv[s];
        float2 hh = h3[s];
        a0 += w * hh.x;
        a1 += w * hh.y;
    }
    float dn = dinv[n];
    float2 yy = y3[n];
    float z0 = dn * a0 + yy.x;
    float z1 = dn * a1 + yy.y;
    float m = fmaxf(z0, z1);
    float l = m + logf(expf(z0 - m) + expf(z1 - m));
    out[n * 2 + 0] = z0 - l;
    out[n * 2 + 1] = z1 - l;
}

// ---------------- fused dense ----------------

// t = relu(aggx @ W1 + x @ V1 + b1); also emits bf16 copy tb. 4 nodes/block.
__global__ void k_dense1f(const float* __restrict__ aggx, const float* __restrict__ x,
                          const float* __restrict__ W, const float* __restrict__ V,
                          const float* __restrict__ b, float* __restrict__ tout,
                          unsigned short* __restrict__ tb, int N) {
    __shared__ float sW[640], sV[640];
    for (int i = threadIdx.x; i < 640; i += 256) { sW[i] = W[i]; sV[i] = V[i]; }
    __syncthreads();
    int idx = blockIdx.x * 4 + (threadIdx.x >> 6);
    if (idx >= N) return;
    int f = threadIdx.x & 63;
    float av = (f < 10) ? aggx[(size_t)idx * 10 + f] : 0.0f;
    float xv = (f < 10) ? x[(size_t)idx * 10 + f] : 0.0f;
    float acc = b[f];
#pragma unroll
    for (int k = 0; k < 10; ++k) {
        acc += __shfl(av, k) * sW[k * HID + f];
        acc += __shfl(xv, k) * sV[k * HID + f];
    }
    float r = fmaxf(acc, 0.0f);
    tout[(size_t)idx * HID + f] = r;
    // RTNE fp32 -> bf16 (r is finite, non-NaN)
    unsigned int u = __float_as_uint(r);
    tb[(size_t)idx * HID + f] = (unsigned short)((u + 0x7fffu + ((u >> 16) & 1u)) >> 16);
}

// t = relu(aggt @ W2 + t @ V2 + b2). Register-tiled GEMM: 64 nodes x 64 feats
// per block, thread computes 4x4. In-place safe (block reads only its own rows
// into LDS before writing).
__global__ __launch_bounds__(256) void k_dense2g(
        const float* __restrict__ aggt, const float* __restrict__ tin,
        const float* __restrict__ W, const float* __restrict__ V,
        const float* __restrict__ b, float* __restrict__ tout, int N) {
    __shared__ __align__(16) float sA[64 * 64];  // aggt^T  [k][n]
    __shared__ __align__(16) float sC[64 * 64];  // t^T     [k][n]
    __shared__ __align__(16) float sW[64 * 64];  // [k][f]
    __shared__ __align__(16) float sV[64 * 64];  // [k][f]
    int tid = threadIdx.x;
    int base = blockIdx.x * 64;
    {   // weights: straight copy
        const float4* W4 = (const float4*)W;
        const float4* V4 = (const float4*)V;
        float4* sW4 = (float4*)sW;
        float4* sV4 = (float4*)sV;
        for (int i = tid; i < 1024; i += 256) { sW4[i] = W4[i]; sV4[i] = V4[i]; }
    }
    {   // A tiles: coalesced float4 read, transposed scalar LDS write
        int n = tid >> 2;
        int ks = (tid & 3) * 16;
        int g = base + n;
        if (g < N) {
            const float4* ar = (const float4*)(aggt + (size_t)g * HID + ks);
            const float4* cr = (const float4*)(tin + (size_t)g * HID + ks);
#pragma unroll
            for (int i = 0; i < 4; ++i) {
                float4 a = ar[i], c = cr[i];
                int k = ks + 4 * i;
                sA[(k + 0) * 64 + n] = a.x; sA[(k + 1) * 64 + n] = a.y;
                sA[(k + 2) * 64 + n] = a.z; sA[(k + 3) * 64 + n] = a.w;
                sC[(k + 0) * 64 + n] = c.x; sC[(k + 1) * 64 + n] = c.y;
                sC[(k + 2) * 64 + n] = c.z; sC[(k + 3) * 64 + n] = c.w;
            }
        } else {
#pragma unroll
            for (int i = 0; i < 4; ++i) {
                int k = ks + 4 * i;
#pragma unroll
                for (int j = 0; j < 4; ++j) {
                    sA[(k + j) * 64 + n] = 0.0f;
                    sC[(k + j) * 64 + n] = 0.0f;
                }
            }
        }
    }
    __syncthreads();
    int tx = tid & 15, ty = tid >> 4;
    int f0 = tx * 4, n0 = ty * 4;
    float acc[4][4] = {};
#pragma unroll 8
    for (int k = 0; k < 64; ++k) {
        float4 a = *(const float4*)&sA[k * 64 + n0];
        float4 c = *(const float4*)&sC[k * 64 + n0];
        float4 w = *(const float4*)&sW[k * 64 + f0];
        float4 v = *(const float4*)&sV[k * 64 + f0];
        float aa[4] = {a.x, a.y, a.z, a.w}, cc[4] = {c.x, c.y, c.z, c.w};
        float ww[4] = {w.x, w.y, w.z, w.w}, vv[4] = {v.x, v.y, v.z, v.w};
#pragma unroll
        for (int i = 0; i < 4; ++i)
#pragma unroll
            for (int j = 0; j < 4; ++j)
                acc[i][j] += aa[i] * ww[j] + cc[i] * vv[j];
    }
    float4 bb = *(const float4*)&b[f0];
    float bv[4] = {bb.x, bb.y, bb.z, bb.w};
#pragma unroll
    for (int i = 0; i < 4; ++i) {
        int g = base + n0 + i;
        if (g < N) {
            float4 o;
            o.x = fmaxf(acc[i][0] + bv[0], 0.0f);
            o.y = fmaxf(acc[i][1] + bv[1], 0.0f);
            o.z = fmaxf(acc[i][2] + bv[2], 0.0f);
            o.w = fmaxf(acc[i][3] + bv[3], 0.0f);
            *(float4*)(tout + (size_t)g * HID + f0) = o;
        }
    }
}

// h3 = t @ W3 [N,2], y3 = t @ V3 + b3 [N,2]. 64-node tile through padded LDS.
__global__ void k_dense3(const float* __restrict__ xin, const float* __restrict__ W,
                         const float* __restrict__ V, const float* __restrict__ b,
                         float* __restrict__ h, float* __restrict__ y, int N) {
    __shared__ float s[64][65];
    int base = blockIdx.x * 64;
    int lane = threadIdx.x;
#pragma unroll 8
    for (int r = 0; r < 64; ++r) {
        int n = base + r;
        s[r][lane] = (n < N) ? xin[(size_t)n * HID + lane] : 0.0f;
    }
    __syncthreads();
    int n = base + lane;
    if (n < N) {
        float h0 = 0, h1 = 0, y0 = 0, y1 = 0;
#pragma unroll
        for (int k = 0; k < HID; ++k) {
            float xv = s[lane][k];
            h0 += xv * W[k * 2 + 0];
            h1 += xv * W[k * 2 + 1];
            y0 += xv * V[k * 2 + 0];
            y1 += xv * V[k * 2 + 1];
        }
        h[n * 2 + 0] = h0;
        h[n * 2 + 1] = h1;
        y[n * 2 + 0] = y0 + b[0];
        y[n * 2 + 1] = y1 + b[1];
    }
}

// ---------------- launch ----------------

extern "C" void kernel_launch(void* const* d_in, const int* in_sizes, int n_in,
                              void* d_out, int out_size, void* d_ws, size_t ws_size,
                              hipStream_t stream) {
    const float* x  = (const float*)d_in[0];
    const int*   ei = (const int*)d_in[1];
    const int*   src = ei;
    const int*   dst = ei + NE;
    const float* W1 = (const float*)d_in[2];
    const float* V1 = (const float*)d_in[3];
    const float* b1 = (const float*)d_in[4];
    const float* W2 = (const float*)d_in[5];
    const float* V2 = (const float*)d_in[6];
    const float* b2 = (const float*)d_in[7];
    const float* W3 = (const float*)d_in[8];
    const float* V3 = (const float*)d_in[9];
    const float* b3 = (const float*)d_in[10];
    float* out = (float*)d_out;

    // workspace layout (float offsets)
    float* ws = (float*)d_ws;
    int*   cnt  = (int*)ws;                       // 100352
    int*   rp   = (int*)(ws + 100352);            // 100608 (NN+1)
    float* dinv = ws + 200960;                    // 100352
    int*   perm = (int*)(ws + 301312);            // NE
    float* t    = ws + 1901312;                   // NN*64
    float* R    = ws + 8301312;                   // NN*64 (aggx / aggt / h3,y3)
    float* aggx = R;
    float* aggt = R;
    float* h3   = R;
    float* y3   = R + 2 * NN;
    unsigned short* tb = (unsigned short*)(ws + 14701312);  // NN*64 ushort = 3.2M floats
    int*   bsum = (int*)(ws + 17901312);          // 128

    const int B = 256;

    // ---- CSR build + dinv ----
    k_zero_i<<<(NN + B - 1) / B, B, 0, stream>>>(cnt, NN);
    k_count<<<(NE + B - 1) / B, B, 0, stream>>>(dst, cnt, NE);
    k_dinv<<<(NN + B - 1) / B, B, 0, stream>>>(cnt, dinv, NN);
    k_scan1<<<SCAN_NB, SCAN_T, 0, stream>>>(cnt, rp, bsum, NN);
    k_scan2<<<1, 128, 0, stream>>>(bsum, SCAN_NB);
    k_scan3<<<SCAN_NB, SCAN_T, 0, stream>>>(rp, bsum, NN, NE);
    k_zero_i<<<(NN + B - 1) / B, B, 0, stream>>>(cnt, NN);   // reuse as cursor
    k_fill<<<(NE + B - 1) / B, B, 0, stream>>>(src, dst, rp, cnt, perm, NE);

    // ---- layer 1: aggregate x (10-wide) then fused dense (emits fp32 t + bf16 tb) ----
    k_aggx<<<(NN + B - 1) / B, B, 0, stream>>>(rp, perm, dinv, x, aggx, NN);
    k_dense1f<<<(NN + 3) / 4, B, 0, stream>>>(aggx, x, W1, V1, b1, t, tb, NN);

    // ---- layer 2: bf16 gather-aggregate, then tiled GEMM (in-place on t) ----
    k_agg64b<<<(NN * 64 + B - 1) / B, B, 0, stream>>>(rp, perm, dinv, tb, aggt, NN);
    k_dense2g<<<(NN + 63) / 64, B, 0, stream>>>(aggt, t, W2, V2, b2, t, NN);

    // ---- layer 3: dense to 2-wide, then aggregate (2-wide) + log_softmax ----
    k_dense3<<<(NN + 63) / 64, 64, 0, stream>>>(t, W3, V3, b3, h3, y3, NN);
    k_agg3lsm<<<(NN + B - 1) / B, B, 0, stream>>>(rp, perm, dinv, (const float2*)h3,
                                                  (const float2*)y3, out, NN);
}